// Round 4
// baseline (534.192 us; speedup 1.0000x reference)
//
#include <hip/hip_runtime.h>
#include <hip/hip_bf16.h>

#define N_NODES 100000
#define FEAT 256
#define LATC2 128            // concat(mu, logvar) feature width
#define NEG_SLOPE 0.01f
#define NBUK 782             // ceil(100000 / 128) buckets by dst>>7
#define BCAP 5120            // bucket capacity: mean 4096+128self+pad, 6 sigma headroom

using bf16x8 = __attribute__((ext_vector_type(8))) __bf16;
using f32x4  = __attribute__((ext_vector_type(4))) float;
using ushort8 = __attribute__((ext_vector_type(8))) unsigned short;

// ---------- helpers ----------
__device__ __forceinline__ unsigned short f2bf(float f) {
    unsigned int u = __float_as_uint(f);
    unsigned int r = u + 0x7fffu + ((u >> 16) & 1u);   // RNE
    return (unsigned short)(r >> 16);
}
__device__ __forceinline__ float bf2f(unsigned short u) {
    return __uint_as_float(((unsigned int)u) << 16);
}
__device__ __forceinline__ void gload_lds16(const void* g, void* l) {
    __builtin_amdgcn_global_load_lds(
        (const __attribute__((address_space(1))) void*)g,
        (__attribute__((address_space(3))) void*)l, 16, 0, 0);
}

// ---------- edge-index dtype detection (int64 vs int32) ----------
__global__ void k_detect(const int* __restrict__ ei, int* __restrict__ flag) {
    if (threadIdx.x == 0) {
        int nz = 0;
        for (int i = 0; i < 64; ++i) nz |= ei[2 * i + 1];
        *flag = (nz == 0) ? 2 : 1;   // stride in int32 units per element
    }
}

// ---------- pass 1: bucket edges by dst>>7 into per-bucket regions ----------
__global__ void k_bucket(const int* __restrict__ ei, const int* __restrict__ flag,
                         int* __restrict__ bcnt, int2* __restrict__ ebuf, int E) {
    __shared__ int lcnt[NBUK];
    __shared__ int lbase[NBUK];
    const int t = threadIdx.x;
    const int s = *flag;
    for (int i = t; i < NBUK; i += 256) lcnt[i] = 0;
    __syncthreads();
    const int per = (E + gridDim.x - 1) / gridDim.x;
    const int e0 = blockIdx.x * per;
    const int e1 = min(e0 + per, E);
    for (int e = e0 + t; e < e1; e += 256) {
        const int d = ei[(size_t)(E + e) * s];
        atomicAdd(&lcnt[d >> 7], 1);
    }
    __syncthreads();
    for (int i = t; i < NBUK; i += 256) {
        const int c = lcnt[i];
        lbase[i] = c ? atomicAdd(&bcnt[i], c) : 0;
        lcnt[i] = 0;
    }
    __syncthreads();
    for (int e = e0 + t; e < e1; e += 256) {
        const int sv = ei[(size_t)e * s];
        const int dv = ei[(size_t)(E + e) * s];
        const int b = dv >> 7;
        const int p = lbase[b] + atomicAdd(&lcnt[b], 1);
        if (p < BCAP) ebuf[(size_t)b * BCAP + p] = make_int2(sv, dv);
    }
}

// ---------- pass 2: per-bucket CSR build (self-loop + pad-to-4 w/ zero-row idx) ----------
// node v's region: [start, start+region), region = (deg+1 self + pad) rounded to 4.
// slot 0 = v itself (self loop); pads = N_NODES (a zeroed row).
__global__ void k_csr(const int2* __restrict__ ebuf, const int* __restrict__ bcnt,
                      int* __restrict__ csr, int* __restrict__ rowp0,
                      int* __restrict__ rowe, float* __restrict__ dis) {
    __shared__ int ncnt[128];
    __shared__ int nexcl[128];
    __shared__ int nstart[128];
    const int t = threadIdx.x;
    const int b = blockIdx.x;
    const int nb = b << 7;
    if (t < 128) ncnt[t] = 0;
    __syncthreads();
    const int cnt = min(bcnt[b], BCAP);
    const int2* eb = ebuf + (size_t)b * BCAP;
    for (int i = t; i < cnt; i += 256) atomicAdd(&ncnt[eb[i].y - nb], 1);
    __syncthreads();
    const int own = (t < 128) ? ncnt[t] : 0;
    const int region = (t < 128) ? ((own + 4) & ~3) : 0;   // own edges + 1 self, pad to 4
    if (t < 128) nexcl[t] = region;
    __syncthreads();
    for (int off = 1; off < 128; off <<= 1) {
        int v = 0;
        if (t < 128 && t >= off) v = nexcl[t - off];
        __syncthreads();
        if (t < 128) nexcl[t] += v;
        __syncthreads();
    }
    if (t < 128) {
        const int excl = nexcl[t] - region;     // aligned start (regions are mult-of-4)
        const int v = nb + t;
        if (v < N_NODES) {
            rowp0[v] = b * BCAP + excl;
            rowe[v]  = b * BCAP + excl + region;
            dis[v]   = rsqrtf((float)(own + 1));
            if (excl < BCAP) csr[(size_t)b * BCAP + excl] = v;          // self edge
            for (int i = own + 1; i < region; ++i)
                if (excl + i < BCAP) csr[(size_t)b * BCAP + excl + i] = N_NODES;  // pad
        }
        nstart[t] = excl + 1;
        ncnt[t] = 0;                             // fill cursor
    }
    __syncthreads();
    for (int i = t; i < cnt; i += 256) {
        const int2 e = eb[i];
        const int li = e.y - nb;
        const int p = nstart[li] + atomicAdd(&ncnt[li], 1);
        if (p < BCAP) csr[(size_t)b * BCAP + p] = e.x;
    }
}

// ---------- fp32 -> bf16 convert of x ----------
__global__ void k_cvt_x(const float* __restrict__ x, unsigned short* __restrict__ xb) {
    const size_t i = ((size_t)blockIdx.x * 256 + threadIdx.x) * 4;   // exact cover
    float4 f = *reinterpret_cast<const float4*>(&x[i]);
    ushort4 u;
    u.x = f2bf(f.x); u.y = f2bf(f.y); u.z = f2bf(f.z); u.w = f2bf(f.w);
    *reinterpret_cast<ushort4*>(&xb[i]) = u;
}

// ---------- weights: transpose + convert ----------
__global__ void k_cvt_w(const float* __restrict__ Wsh, const float* __restrict__ Wmu,
                        const float* __restrict__ Wlv,
                        unsigned short* __restrict__ Wt, unsigned short* __restrict__ Wct) {
    const int i = blockIdx.x * 256 + threadIdx.x;   // 65536 threads
    {
        const int n = i >> 8, k = i & 255;
        Wt[(size_t)n * 256 + k] = f2bf(Wsh[(size_t)k * 256 + n]);
    }
    if (i < 128 * 256) {
        const int n = i >> 8, k = i & 255;
        const float v = (n < 64) ? Wmu[(size_t)k * 64 + n] : Wlv[(size_t)k * 64 + (n - 64)];
        Wct[(size_t)n * 256 + k] = f2bf(v);
    }
}

// ---------- bf16 MFMA GEMM: C[M,NC] = scale[row] * (A[M,256] @ Bt[NC,256]^T) ----------
template<int NC>
__global__ void k_gemm(const unsigned short* __restrict__ A,
                       const unsigned short* __restrict__ Bt,
                       unsigned short* __restrict__ C,
                       const float* __restrict__ scale, int M) {
    constexpr int WN  = NC / 4;
    constexpr int NFR = WN / 16;
    __shared__ __align__(16) unsigned short lA[64 * 32];
    __shared__ __align__(16) unsigned short lB[NC * 32];
    const int t = threadIdx.x;
    const int w = t >> 6, l = t & 63;
    const int l15 = l & 15, lh = l >> 4;
    const int rowbase = blockIdx.x * 64;

    f32x4 acc[4][NFR];
#pragma unroll
    for (int mi = 0; mi < 4; ++mi)
#pragma unroll
        for (int nj = 0; nj < NFR; ++nj)
            acc[mi][nj] = (f32x4){0.f, 0.f, 0.f, 0.f};

    const int sr = t >> 2, sl = t & 3;
    int grA = rowbase + sr; if (grA > M - 1) grA = M - 1;   // clamp tail rows

#pragma unroll 1
    for (int ks = 0; ks < 8; ++ks) {
        const int k0 = ks * 32;
        gload_lds16(A + ((size_t)grA * FEAT + k0 + sl * 8), &lA[(size_t)t * 8]);
#pragma unroll
        for (int j = 0; j < NC / 64; ++j)
            gload_lds16(Bt + ((size_t)(j * 64 + sr) * FEAT + k0 + sl * 8),
                        &lB[(size_t)j * 2048 + (size_t)t * 8]);
        asm volatile("s_waitcnt vmcnt(0)" ::: "memory");
        __syncthreads();

        bf16x8 a[4];
#pragma unroll
        for (int mi = 0; mi < 4; ++mi)
            a[mi] = *reinterpret_cast<const bf16x8*>(&lA[(mi * 16 + l15) * 32 + lh * 8]);
#pragma unroll
        for (int nj = 0; nj < NFR; ++nj) {
            bf16x8 b = *reinterpret_cast<const bf16x8*>(&lB[(w * WN + nj * 16 + l15) * 32 + lh * 8]);
#pragma unroll
            for (int mi = 0; mi < 4; ++mi)
                acc[mi][nj] = __builtin_amdgcn_mfma_f32_16x16x32_bf16(a[mi], b, acc[mi][nj], 0, 0, 0);
        }
        __syncthreads();
    }

#pragma unroll
    for (int mi = 0; mi < 4; ++mi) {
#pragma unroll
        for (int r = 0; r < 4; ++r) {
            const int row = rowbase + mi * 16 + lh * 4 + r;
            if (row < M) {
                const float sc = scale[row];
#pragma unroll
                for (int nj = 0; nj < NFR; ++nj) {
                    const int col = w * WN + nj * 16 + l15;
                    C[(size_t)row * NC + col] = f2bf(sc * acc[mi][nj][r]);
                }
            }
        }
    }
}

// ---------- aggregation layer 1: h = LeakyReLU(dv * sum h0s[csr[]] + b) ----------
// one wave per node; half-wave per group of 4 edges (int4 csr broadcast);
// 4 independent 512B row gathers per half -> 8 rows in flight per wave.
__global__ void k_agg1(const unsigned short* __restrict__ h0s,
                       const int* __restrict__ rowp0, const int* __restrict__ rowe,
                       const int* __restrict__ csr,
                       const float* __restrict__ dis, const float* __restrict__ bias,
                       unsigned short* __restrict__ hout) {
    const int w = threadIdx.x >> 6, l = threadIdx.x & 63;
    const int v = blockIdx.x * 4 + w;
    if (v >= N_NODES) return;
    const int h = l >> 5, li = l & 31;
    const int p0 = rowp0[v], p1 = rowe[v];

    float acc[8];
#pragma unroll
    for (int j = 0; j < 8; ++j) acc[j] = 0.f;

    for (int g = p0 + h * 4; g < p1; g += 8) {
        const int4 s4 = *reinterpret_cast<const int4*>(&csr[g]);
        ushort8 u0 = *reinterpret_cast<const ushort8*>(&h0s[(size_t)s4.x * FEAT + li * 8]);
        ushort8 u1 = *reinterpret_cast<const ushort8*>(&h0s[(size_t)s4.y * FEAT + li * 8]);
        ushort8 u2 = *reinterpret_cast<const ushort8*>(&h0s[(size_t)s4.z * FEAT + li * 8]);
        ushort8 u3 = *reinterpret_cast<const ushort8*>(&h0s[(size_t)s4.w * FEAT + li * 8]);
#pragma unroll
        for (int j = 0; j < 8; ++j) acc[j] += bf2f(u0[j]);
#pragma unroll
        for (int j = 0; j < 8; ++j) acc[j] += bf2f(u1[j]);
#pragma unroll
        for (int j = 0; j < 8; ++j) acc[j] += bf2f(u2[j]);
#pragma unroll
        for (int j = 0; j < 8; ++j) acc[j] += bf2f(u3[j]);
    }

#pragma unroll
    for (int j = 0; j < 8; ++j) acc[j] += __shfl_xor(acc[j], 32, 64);

    if (h == 0) {
        const float dv = dis[v];
        const int c = li * 8;
        ushort8 r;
#pragma unroll
        for (int j = 0; j < 8; ++j) {
            float o = dv * acc[j] + bias[c + j];
            o = (o >= 0.f) ? o : NEG_SLOPE * o;
            r[j] = f2bf(o);
        }
        *reinterpret_cast<ushort8*>(&hout[(size_t)v * FEAT + c]) = r;
    }
}

// ---------- aggregation layer 2: quarter-wave per group of 4 edges; 16 rows in flight ----------
__global__ void k_agg2(const unsigned short* __restrict__ hcs,
                       const int* __restrict__ rowp0, const int* __restrict__ rowe,
                       const int* __restrict__ csr,
                       const float* __restrict__ dis,
                       const float* __restrict__ bmu, const float* __restrict__ blv,
                       float* __restrict__ out) {
    const int w = threadIdx.x >> 6, l = threadIdx.x & 63;
    const int v = blockIdx.x * 4 + w;
    if (v >= N_NODES) return;
    const int q = l >> 4, li = l & 15;
    const int p0 = rowp0[v], p1 = rowe[v];

    float acc[8];
#pragma unroll
    for (int j = 0; j < 8; ++j) acc[j] = 0.f;

    for (int g = p0 + q * 4; g < p1; g += 16) {
        const int4 s4 = *reinterpret_cast<const int4*>(&csr[g]);
        ushort8 u0 = *reinterpret_cast<const ushort8*>(&hcs[(size_t)s4.x * LATC2 + li * 8]);
        ushort8 u1 = *reinterpret_cast<const ushort8*>(&hcs[(size_t)s4.y * LATC2 + li * 8]);
        ushort8 u2 = *reinterpret_cast<const ushort8*>(&hcs[(size_t)s4.z * LATC2 + li * 8]);
        ushort8 u3 = *reinterpret_cast<const ushort8*>(&hcs[(size_t)s4.w * LATC2 + li * 8]);
#pragma unroll
        for (int j = 0; j < 8; ++j) acc[j] += bf2f(u0[j]);
#pragma unroll
        for (int j = 0; j < 8; ++j) acc[j] += bf2f(u1[j]);
#pragma unroll
        for (int j = 0; j < 8; ++j) acc[j] += bf2f(u2[j]);
#pragma unroll
        for (int j = 0; j < 8; ++j) acc[j] += bf2f(u3[j]);
    }

#pragma unroll
    for (int j = 0; j < 8; ++j) acc[j] += __shfl_xor(acc[j], 16, 64);
#pragma unroll
    for (int j = 0; j < 8; ++j) acc[j] += __shfl_xor(acc[j], 32, 64);

    if (l < 16) {
        const float dv = dis[v];
        const int c = li * 8;   // feature base in [0,128)
        float o[8];
        if (c < 64) {
#pragma unroll
            for (int j = 0; j < 8; ++j) o[j] = dv * acc[j] + bmu[c + j];
            float4 o0 = {o[0], o[1], o[2], o[3]};
            float4 o1 = {o[4], o[5], o[6], o[7]};
            *reinterpret_cast<float4*>(&out[(size_t)v * 64 + c])     = o0;
            *reinterpret_cast<float4*>(&out[(size_t)v * 64 + c + 4]) = o1;
        } else {
            const int cc = c - 64;
#pragma unroll
            for (int j = 0; j < 8; ++j) o[j] = fminf(dv * acc[j] + blv[cc + j], 10.0f);
            float4 o0 = {o[0], o[1], o[2], o[3]};
            float4 o1 = {o[4], o[5], o[6], o[7]};
            *reinterpret_cast<float4*>(&out[(size_t)N_NODES * 64 + (size_t)v * 64 + cc])     = o0;
            *reinterpret_cast<float4*>(&out[(size_t)N_NODES * 64 + (size_t)v * 64 + cc + 4]) = o1;
        }
    }
}

extern "C" void kernel_launch(void* const* d_in, const int* in_sizes, int n_in,
                              void* d_out, int out_size, void* d_ws, size_t ws_size,
                              hipStream_t stream) {
    const float* x   = (const float*)d_in[0];
    const int*   ei  = (const int*)d_in[1];
    const float* Wsh = (const float*)d_in[2];
    const float* bsh = (const float*)d_in[3];
    const float* Wmu = (const float*)d_in[4];
    const float* bmu = (const float*)d_in[5];
    const float* Wlv = (const float*)d_in[6];
    const float* blv = (const float*)d_in[7];
    const int E = in_sizes[1] / 2;

    char* base = (char*)d_ws;
    size_t off = 0;
    auto take = [&](size_t bytes) -> char* {
        char* r = base + off;
        off += (bytes + 511) & ~(size_t)511;
        return r;
    };
    int*   flag  = (int*)take(4);
    int*   bcnt  = (int*)take((size_t)NBUK * 4);
    int*   rowp0 = (int*)take((size_t)N_NODES * 4);
    int*   rowe  = (int*)take((size_t)N_NODES * 4);
    float* dis   = (float*)take((size_t)N_NODES * 4);
    int*   csr   = (int*)take((size_t)NBUK * BCAP * 4);                       // 16.0 MB
    unsigned short* bufA = (unsigned short*)take((size_t)N_NODES * FEAT * 2); // 51.2 MB
    unsigned short* bufB = (unsigned short*)take(((size_t)N_NODES + 1) * FEAT * 2); // +zero row
    unsigned short* Wt   = (unsigned short*)take(256 * 256 * 2);
    unsigned short* Wct  = (unsigned short*)take(128 * 256 * 2);
    // ebuf (32 MB) aliases bufB: ebuf is dead before k_gemm<256> writes bufB.
    int2* ebuf = (int2*)bufB;

    hipMemsetAsync(bcnt, 0, (size_t)NBUK * 4, stream);
    k_detect<<<1, 64, 0, stream>>>(ei, flag);
    k_bucket<<<256, 256, 0, stream>>>(ei, flag, bcnt, ebuf, E);
    k_csr<<<NBUK, 256, 0, stream>>>(ebuf, bcnt, csr, rowp0, rowe, dis);
    k_cvt_x<<<25000, 256, 0, stream>>>(x, bufA);
    k_cvt_w<<<256, 256, 0, stream>>>(Wsh, Wmu, Wlv, Wt, Wct);
    // zero row N_NODES for the 256-wide h0s buffer (pads gather from it)
    hipMemsetAsync(bufB + (size_t)N_NODES * FEAT, 0, FEAT * 2, stream);
    k_gemm<256><<<(N_NODES + 63) / 64, 256, 0, stream>>>(bufA, Wt, bufB, dis, N_NODES);     // h0s
    k_agg1<<<(N_NODES + 3) / 4, 256, 0, stream>>>(bufB, rowp0, rowe, csr, dis, bsh, bufA);  // h
    // zero row N_NODES for the 128-wide hcs buffer (safe: h0s dead after agg1)
    hipMemsetAsync(bufB + (size_t)N_NODES * LATC2, 0, LATC2 * 2, stream);
    k_gemm<128><<<(N_NODES + 63) / 64, 256, 0, stream>>>(bufA, Wct, bufB, dis, N_NODES);    // hcs
    k_agg2<<<(N_NODES + 3) / 4, 256, 0, stream>>>(bufB, rowp0, rowe, csr, dis, bmu, blv, (float*)d_out);
}